// Round 17
// baseline (238.867 us; speedup 1.0000x reference)
//
#include <hip/hip_runtime.h>
#include <stdint.h>

#define BATCH 4
#define SEQ   1024
#define NHEAD 16
#define DHEAD 128
#define HDIM  2048
#define GM    4096   /* BATCH*SEQ */
#define GN    2048
#define GK    2048

typedef __attribute__((ext_vector_type(8)))  short    short8;
typedef __attribute__((ext_vector_type(4)))  float    f32x4;
typedef __attribute__((ext_vector_type(16))) float    f32x16;
typedef __attribute__((ext_vector_type(4)))  uint32_t u32x4;

__device__ __forceinline__ uint16_t f2bf(float f) {
  uint32_t u = __builtin_bit_cast(uint32_t, f);
  u += 0x7fffu + ((u >> 16) & 1u);
  return (uint16_t)(u >> 16);
}
__device__ __forceinline__ float bf2f(uint16_t h) {
  return __builtin_bit_cast(float, (uint32_t)h << 16);
}
__device__ __forceinline__ uint32_t cvtpk(float lo, float hi) {
  uint32_t r;
  asm("v_cvt_pk_bf16_f32 %0, %1, %2" : "=v"(r) : "v"(lo), "v"(hi));
  return r;
}

// XOR swizzles (involutions) for 128B/256B LDS rows
__device__ __forceinline__ uint32_t swz128(uint32_t a) { return a ^ (((a >> 7) & 7u) << 4); }
__device__ __forceinline__ uint32_t swz256(uint32_t a) { return a ^ (((a >> 8) & 7u) << 4); }

#define GAS __attribute__((address_space(1)))
#define LAS __attribute__((address_space(3)))
__device__ __forceinline__ void gload_lds16(const void* g, void* l) {
  __builtin_amdgcn_global_load_lds((GAS const void*)g, (LAS void*)l, 16, 0, 0);
}

// ---------------- fp32 -> bf16 convert (hs + 4 weights), grid-stride @2048 blocks ----------------
// 3,145,728 8-elem groups total: [0, 1M) = hs -> Xbf; rest = W0..W3 -> Wb (each 2^19 groups).
__global__ void cvt_all_kernel(const float* __restrict__ hs,
                               const float* __restrict__ W0, const float* __restrict__ W1,
                               const float* __restrict__ W2, const float* __restrict__ W3,
                               uint16_t* __restrict__ Xbf, uint16_t* __restrict__ Wb) {
  const uint32_t NX = 1048576u;          // GM*HDIM/8
  const uint32_t NTOT = 3145728u;        // NX + 4*HDIM*HDIM/8
  for (uint32_t g = blockIdx.x * 256 + threadIdx.x; g < NTOT; g += 2048 * 256) {
    const float* src; uint16_t* dst;
    if (g < NX) {
      src = hs + (size_t)g * 8;
      dst = Xbf + (size_t)g * 8;
    } else {
      const uint32_t gw = g - NX;
      const uint32_t m = gw >> 19, off = gw & 524287u;
      const float* Ws = (m == 0) ? W0 : (m == 1) ? W1 : (m == 2) ? W2 : W3;
      src = Ws + (size_t)off * 8;
      dst = Wb + (size_t)m * HDIM * HDIM + (size_t)off * 8;
    }
    const float4* p = (const float4*)src;
    float4 a = p[0], b = p[1];
    uint32_t w0 = f2bf(a.x) | ((uint32_t)f2bf(a.y) << 16);
    uint32_t w1 = f2bf(a.z) | ((uint32_t)f2bf(a.w) << 16);
    uint32_t w2 = f2bf(b.x) | ((uint32_t)f2bf(b.y) << 16);
    uint32_t w3 = f2bf(b.z) | ((uint32_t)f2bf(b.w) << 16);
    int4 r; r.x = (int)w0; r.y = (int)w1; r.z = (int)w2; r.w = (int)w3;
    *(int4*)dst = r;
  }
}

// ---------------- RoPE in-place on k only (q rope fused into attn) ----------------
__global__ void rope_kernel(uint16_t* __restrict__ kb,
                            const float* __restrict__ fcos, const float* __restrict__ fsin) {
  uint32_t i = blockIdx.x * 256 + threadIdx.x;
  uint16_t* p = kb + (size_t)i * 8;
  uint32_t e0 = i * 8;
  uint32_t row = e0 >> 11;
  uint32_t col = e0 & 2047;
  uint32_t s = row & (SEQ - 1);
  uint32_t pi = (col & (DHEAD - 1)) >> 1;
  float4 cv = *(const float4*)(fcos + (size_t)s * 64 + pi);
  float4 sv = *(const float4*)(fsin + (size_t)s * 64 + pi);
  int4 raw = *(const int4*)p;
  uint16_t u[8]; *(int4*)u = raw;
  float cc[4] = {cv.x, cv.y, cv.z, cv.w}, ss[4] = {sv.x, sv.y, sv.z, sv.w};
#pragma unroll
  for (int t = 0; t < 4; ++t) {
    float x0 = bf2f(u[2 * t]), x1 = bf2f(u[2 * t + 1]);
    float o0 = x0 * cc[t] - x1 * ss[t];
    float o1 = x0 * ss[t] + x1 * cc[t];
    u[2 * t] = f2bf(o0); u[2 * t + 1] = f2bf(o1);
  }
  *(int4*)p = *(int4*)u;
}

// ---------------- GEMM (BK=64, 16x16x32 MFMA, measured 1005 TF / 0 conflicts) ----------------
template <int MODE>
__device__ __forceinline__ void gemm_body(const uint16_t* __restrict__ A,
                                          const uint16_t* __restrict__ Bw,
                                          const float* __restrict__ bias,
                                          void* __restrict__ Cout) {
  __shared__ __align__(16) char smA[128 * 128];
  __shared__ __align__(16) char smB[128 * 128];
  const int tid = threadIdx.x, lane = tid & 63, wid = tid >> 6;
  const int c = lane & 15, g = lane >> 4;
  const int row0 = blockIdx.x * 128, col0 = blockIdx.y * 128;
  const int wr = wid >> 1, wc = wid & 1;
  f32x4 acc[4][4] = {};
  const uint32_t oBase = wid * 4096 + lane * 16;

  for (int kk = 0; kk < GK; kk += 64) {
#pragma unroll
    for (int q = 0; q < 4; ++q) {
      uint32_t o = oBase + q * 1024;
      uint32_t r = o >> 7;
      uint32_t cb = (o & 127) ^ ((r & 7u) << 4);
      gload_lds16((const char*)A + ((size_t)(row0 + r) * GK + kk) * 2 + cb,
                  smA + wid * 4096 + q * 1024);
      gload_lds16((const char*)Bw + ((size_t)(col0 + r) * GK + kk) * 2 + cb,
                  smB + wid * 4096 + q * 1024);
    }
    __syncthreads();
    short8 af[4][2], bf[4][2];
#pragma unroll
    for (int m = 0; m < 4; ++m) {
      const uint32_t row = (uint32_t)(wr * 64 + m * 16 + c);
#pragma unroll
      for (int ks = 0; ks < 2; ++ks)
        af[m][ks] = *(const short8*)(smA + row * 128 + (((uint32_t)(ks * 64 + g * 16)) ^ ((row & 7u) << 4)));
    }
#pragma unroll
    for (int n = 0; n < 4; ++n) {
      const uint32_t row = (uint32_t)(wc * 64 + n * 16 + c);
#pragma unroll
      for (int ks = 0; ks < 2; ++ks)
        bf[n][ks] = *(const short8*)(smB + row * 128 + (((uint32_t)(ks * 64 + g * 16)) ^ ((row & 7u) << 4)));
    }
#pragma unroll
    for (int m = 0; m < 4; ++m)
#pragma unroll
      for (int n = 0; n < 4; ++n)
#pragma unroll
        for (int ks = 0; ks < 2; ++ks)
          acc[m][n] = __builtin_amdgcn_mfma_f32_16x16x32_bf16(af[m][ks], bf[n][ks], acc[m][n], 0, 0, 0);
    __syncthreads();
  }

  float bn[4];
#pragma unroll
  for (int n = 0; n < 4; ++n) bn[n] = bias[col0 + wc * 64 + n * 16 + c];
#pragma unroll
  for (int m = 0; m < 4; ++m) {
    const int gr = row0 + wr * 64 + m * 16 + g * 4;
#pragma unroll
    for (int n = 0; n < 4; ++n) {
      const int gc = col0 + wc * 64 + n * 16 + c;
#pragma unroll
      for (int jj = 0; jj < 4; ++jj) {
        float v = acc[m][n][jj] + bn[n];
        if (MODE == 1) ((float*)Cout)[(size_t)(gr + jj) * GN + gc] = v;
        else           ((uint16_t*)Cout)[(size_t)(gr + jj) * GN + gc] = f2bf(v);
      }
    }
  }
}

__global__ __launch_bounds__(256, 2) void gemm_qkv_kernel(
    const uint16_t* __restrict__ X,
    const uint16_t* __restrict__ Wq, const uint16_t* __restrict__ Wk, const uint16_t* __restrict__ Wv,
    const float* __restrict__ bq, const float* __restrict__ bk, const float* __restrict__ bv,
    uint16_t* __restrict__ qo, uint16_t* __restrict__ ko, uint16_t* __restrict__ vo) {
  const uint16_t* W; const float* bias; uint16_t* out;
  if (blockIdx.z == 0)      { W = Wq; bias = bq; out = qo; }
  else if (blockIdx.z == 1) { W = Wk; bias = bk; out = ko; }
  else                      { W = Wv; bias = bv; out = vo; }
  gemm_body<0>(X, W, bias, out);
}

__global__ __launch_bounds__(256, 2) void gemm_out_kernel(
    const uint16_t* __restrict__ ctx, const uint16_t* __restrict__ Wo,
    const float* __restrict__ bo, float* __restrict__ out) {
  gemm_body<1>(ctx, Wo, bo, out);
}

// ---------------- flash attention v7 (r14/r16 session best): 512 thr, 8 waves, dbuf pipeline ----------------
__global__ __launch_bounds__(512, 2) void attn_kernel(
    const uint16_t* __restrict__ q, const uint16_t* __restrict__ k,
    const uint16_t* __restrict__ v, const float* __restrict__ mask,
    const float* __restrict__ fcos, const float* __restrict__ fsin,
    uint16_t* __restrict__ ctx) {
  __shared__ __align__(16) char pool[66048];
  float* smT = (float*)pool;  // epilogue only

  const int tid = threadIdx.x, lane = tid & 63, wid = tid >> 6;  // wid 0..7
  const int c32 = lane & 31, hi = lane >> 5;
  const int lb = (blockIdx.x & 7) * 32 + (blockIdx.x >> 3);
  const int qt = lb & 3, bh = lb >> 2;
  const int h = bh & (NHEAD - 1), b = bh >> 4;
  const int q0 = qt * 256;
  const float scale = 0.022097086912079608f;  // 1/sqrt(2048)

  short8 qreg[8];
  {
    const int srow = q0 + wid * 32 + c32;
    const uint16_t* qrow = q + (size_t)(b * SEQ + srow) * HDIM + h * DHEAD;
#pragma unroll
    for (int ks = 0; ks < 8; ++ks) {
      short8 raw = *(const short8*)(qrow + ks * 16 + hi * 8);
      float4 cv = *(const float4*)(fcos + (size_t)srow * 64 + ks * 8 + hi * 4);
      float4 sv = *(const float4*)(fsin + (size_t)srow * 64 + ks * 8 + hi * 4);
      uint16_t u[8]; *(short8*)u = raw;
      float cc[4] = {cv.x, cv.y, cv.z, cv.w}, ssv[4] = {sv.x, sv.y, sv.z, sv.w};
#pragma unroll
      for (int tp = 0; tp < 4; ++tp) {
        float x0 = bf2f(u[2 * tp]), x1 = bf2f(u[2 * tp + 1]);
        u[2 * tp]     = f2bf(x0 * cc[tp] - x1 * ssv[tp]);
        u[2 * tp + 1] = f2bf(x0 * ssv[tp] + x1 * cc[tp]);
      }
      qreg[ks] = *(short8*)u;
    }
  }

  const int kvq = tid >> 5;          // V-transpose: 4 kv x 4 d per thread
  const int d0v = (tid & 31) * 4;

  auto issueK = [&](int s) {   // 8 waves x 2 gloads = 64 rows
    char* dK = pool + (s & 1) * 16384;
#pragma unroll
    for (int i = 0; i < 2; ++i) {
      uint32_t o_ = wid * 2048 + i * 1024 + lane * 16;
      uint32_t r = o_ >> 8;
      uint32_t cb = swz256(o_) & 255;
      gload_lds16((const char*)k + ((size_t)(b * SEQ + s * 64 + r) * HDIM + h * DHEAD) * 2 + cb,
                  dK + wid * 2048 + i * 1024);
    }
  };
  auto loadV = [&](int s, uint32_t vw[4][2]) {
    const uint16_t* vsrc = v + (size_t)(b * SEQ + s * 64 + kvq * 4) * HDIM + h * DHEAD + d0v;
#pragma unroll
    for (int e = 0; e < 4; ++e) {
      uint2 t2 = *(const uint2*)(vsrc + (size_t)e * HDIM);
      vw[e][0] = t2.x; vw[e][1] = t2.y;
    }
  };
  auto writeVT = [&](int s, uint32_t vw[4][2]) {
    char* dVT = pool + 32768 + (s & 1) * 16384;
#pragma unroll
    for (int j = 0; j < 4; ++j) {
      const int hw = j >> 1, sh = (j & 1) * 16;
      uint2 pk;
      pk.x = ((vw[0][hw] >> sh) & 0xffffu) | (((vw[1][hw] >> sh) & 0xffffu) << 16);
      pk.y = ((vw[2][hw] >> sh) & 0xffffu) | (((vw[3][hw] >> sh) & 0xffffu) << 16);
      *(uint2*)(dVT + swz128((uint32_t)((d0v + j) * 128 + kvq * 8))) = pk;
    }
  };

  float mreg = -1e30f, lreg = 0.f;
  f32x16 o[4] = {};

  {
    float mtmp = 0.f;
    if (tid < 64) mtmp = mask[b * SEQ + tid];
    uint32_t vw[4][2];
    loadV(0, vw);
    issueK(0);
    if (tid < 64) ((float*)(pool + 65536))[tid] = mtmp;
    writeVT(0, vw);
  }
  __syncthreads();

  for (int t = 0; t < 16; ++t) {
    const int cur = t & 1;
    const char* sK  = pool + cur * 16384;
    const char* sVT = pool + 32768 + cur * 16384;
    const float* smMaskF = (const float*)(pool + 65536 + cur * 256);

    float mtmp = 0.f;
    uint32_t vw[4][2];
    if (t < 15) {
      if (tid < 64) mtmp = mask[b * SEQ + (t + 1) * 64 + tid];
      loadV(t + 1, vw);
      issueK(t + 1);
    }

    f32x16 st[2] = {};
    __builtin_amdgcn_s_setprio(1);
#pragma unroll
    for (int ks = 0; ks < 8; ++ks) {
#pragma unroll
      for (int mi = 0; mi < 2; ++mi) {
        const uint32_t row = (uint32_t)(mi * 32 + c32);
        short8 kf = *(const short8*)(sK + row * 256 +
                    (((uint32_t)(ks * 32 + hi * 16)) ^ ((row & 7u) << 4)));
        st[mi] = __builtin_amdgcn_mfma_f32_32x32x16_bf16(kf, qreg[ks], st[mi], 0, 0, 0);
      }
    }
    __builtin_amdgcn_s_setprio(0);

    float pmax = -1e30f;
#pragma unroll
    for (int mi = 0; mi < 2; ++mi) {
      const float* mb = smMaskF + mi * 32 + hi * 4;
      float4 m0 = *(const float4*)(mb);
      float4 m1 = *(const float4*)(mb + 8);
      float4 m2 = *(const float4*)(mb + 16);
      float4 m3 = *(const float4*)(mb + 24);
      float mm[16] = {m0.x, m0.y, m0.z, m0.w, m1.x, m1.y, m1.z, m1.w,
                      m2.x, m2.y, m2.z, m2.w, m3.x, m3.y, m3.z, m3.w};
#pragma unroll
      for (int r = 0; r < 16; ++r) {
        float s = st[mi][r] * scale;
        if (mm[r] == 0.f) s = -1e9f;
        st[mi][r] = s;
        pmax = fmaxf(pmax, s);
      }
    }
    pmax = fmaxf(pmax, __shfl_xor(pmax, 32, 64));

    if (!__all(pmax <= mreg + 8.f)) {
      float mnew = fmaxf(mreg, pmax);
      float fac = __expf(mreg - mnew);
      lreg *= fac;
#pragma unroll
      for (int dt = 0; dt < 4; ++dt)
#pragma unroll
        for (int e = 0; e < 16; ++e) o[dt][e] *= fac;
      mreg = mnew;
    }

    float rsum = 0.f;
    short8 pfrag[4];
#pragma unroll
    for (int mi = 0; mi < 2; ++mi) {
      float pe[16];
#pragma unroll
      for (int r = 0; r < 16; ++r) {
        pe[r] = __expf(st[mi][r] - mreg);
        rsum += pe[r];
      }
      uint32_t w[8], s[8];
#pragma unroll
      for (int j = 0; j < 8; ++j) w[j] = cvtpk(pe[2 * j], pe[2 * j + 1]);
#pragma unroll
      for (int j = 0; j < 8; ++j) s[j] = (uint32_t)__shfl_xor((int)w[j], 32, 64);
      u32x4 f0, f1;
      f0[0] = hi ? s[2] : w[0];  f0[1] = hi ? s[3] : w[1];
      f0[2] = hi ? w[2] : s[0];  f0[3] = hi ? w[3] : s[1];
      f1[0] = hi ? s[6] : w[4];  f1[1] = hi ? s[7] : w[5];
      f1[2] = hi ? w[6] : s[4];  f1[3] = hi ? w[7] : s[5];
      pfrag[mi * 2]     = __builtin_bit_cast(short8, f0);
      pfrag[mi * 2 + 1] = __builtin_bit_cast(short8, f1);
    }
    rsum += __shfl_xor(rsum, 32, 64);
    lreg += rsum;

    if (t < 15) {
      if (tid < 64) ((float*)(pool + 65536 + ((t + 1) & 1) * 256))[tid] = mtmp;
      writeVT(t + 1, vw);
    }

    __builtin_amdgcn_s_setprio(1);
#pragma unroll
    for (int dt = 0; dt < 4; ++dt) {
      const uint32_t row = (uint32_t)(dt * 32 + c32);
#pragma unroll
      for (int e = 0; e < 4; ++e) {
        short8 vf = *(const short8*)(sVT + row * 128 +
                    (((uint32_t)(e * 32 + hi * 16)) ^ ((row & 7u) << 4)));
        o[dt] = __builtin_amdgcn_mfma_f32_32x32x16_bf16(vf, pfrag[e], o[dt], 0, 0, 0);
      }
    }
    __builtin_amdgcn_s_setprio(0);

    __syncthreads();
  }

  const float linv = 1.f / lreg;
  float* myT = smT + wid * (32 * 36);
  const int qe = lane >> 1, de0 = (lane & 1) * 16;
#pragma unroll
  for (int dt = 0; dt < 4; ++dt) {
#pragma unroll
    for (int r = 0; r < 16; ++r) {
      const int drow = (r & 3) + 8 * (r >> 2) + 4 * hi;
      myT[c32 * 36 + drow] = o[dt][r] * linv;   // [q][d]
    }
    float vv[16];
#pragma unroll
    for (int j = 0; j < 4; ++j) {
      float4 rd = *(const float4*)(myT + qe * 36 + de0 + j * 4);
      vv[j * 4 + 0] = rd.x; vv[j * 4 + 1] = rd.y; vv[j * 4 + 2] = rd.z; vv[j * 4 + 3] = rd.w;
    }
    uint32_t pw[8];
#pragma unroll
    for (int m = 0; m < 8; ++m)
      pw[m] = f2bf(vv[2 * m]) | ((uint32_t)f2bf(vv[2 * m + 1]) << 16);
    uint16_t* dst = ctx + (size_t)(b * SEQ + q0 + wid * 32 + qe) * HDIM + h * DHEAD + dt * 32 + de0;
    int4 s0; s0.x = (int)pw[0]; s0.y = (int)pw[1]; s0.z = (int)pw[2]; s0.w = (int)pw[3];
    int4 s1; s1.x = (int)pw[4]; s1.y = (int)pw[5]; s1.z = (int)pw[6]; s1.w = (int)pw[7];
    *(int4*)(dst) = s0;
    *(int4*)(dst + 8) = s1;
  }
}

// ---------------- launch ----------------
extern "C" void kernel_launch(void* const* d_in, const int* in_sizes, int n_in,
                              void* d_out, int out_size, void* d_ws, size_t ws_size,
                              hipStream_t stream) {
  const float* hs   = (const float*)d_in[0];
  const float* fcos = (const float*)d_in[1];
  const float* fsin = (const float*)d_in[2];
  const float* mask = (const float*)d_in[3];
  const float* Wq = (const float*)d_in[4];  const float* bq = (const float*)d_in[5];
  const float* Wk = (const float*)d_in[6];  const float* bk = (const float*)d_in[7];
  const float* Wv = (const float*)d_in[8];  const float* bv = (const float*)d_in[9];
  const float* Wo = (const float*)d_in[10]; const float* bo = (const float*)d_in[11];
  float* out = (float*)d_out;

  char* ws = (char*)d_ws;
  const size_t XB = (size_t)GM * HDIM * 2;    // 16 MB
  const size_t WB = (size_t)HDIM * HDIM * 2;  //  8 MB
  uint16_t* Xbf = (uint16_t*)(ws);            // reused as ctx after QKV
  uint16_t* Wqb = (uint16_t*)(ws + XB);       // Wqb..Wob contiguous
  uint16_t* Wkb = (uint16_t*)(ws + XB + WB);
  uint16_t* Wvb = (uint16_t*)(ws + XB + 2 * WB);
  uint16_t* Wob = (uint16_t*)(ws + XB + 3 * WB);
  uint16_t* qb  = (uint16_t*)(ws + XB + 4 * WB);
  uint16_t* kb  = (uint16_t*)(ws + XB + 4 * WB + XB);
  uint16_t* vb  = (uint16_t*)(ws + XB + 4 * WB + 2 * XB);

  cvt_all_kernel<<<2048, 256, 0, stream>>>(hs, Wq, Wk, Wv, Wo, Xbf, Wqb);

  gemm_qkv_kernel<<<dim3(GM / 128, GN / 128, 3), 256, 0, stream>>>(
      Xbf, Wqb, Wkb, Wvb, bq, bk, bv, qb, kb, vb);

  rope_kernel<<<dim3((GM * HDIM) / 8 / 256, 1, 1), 256, 0, stream>>>(kb, fcos, fsin);

  attn_kernel<<<256, 512, 0, stream>>>(qb, kb, vb, mask, fcos, fsin, Xbf);

  gemm_out_kernel<<<dim3(GM / 128, GN / 128, 1), 256, 0, stream>>>(Xbf, Wob, bo, out);
}

// Round 18
// 237.223 us; speedup vs baseline: 1.0069x; 1.0069x over previous
//
#include <hip/hip_runtime.h>
#include <stdint.h>

#define BATCH 4
#define SEQ   1024
#define NHEAD 16
#define DHEAD 128
#define HDIM  2048
#define GM    4096   /* BATCH*SEQ */
#define GN    2048
#define GK    2048

typedef __attribute__((ext_vector_type(8)))  short    short8;
typedef __attribute__((ext_vector_type(4)))  float    f32x4;
typedef __attribute__((ext_vector_type(16))) float    f32x16;
typedef __attribute__((ext_vector_type(4)))  uint32_t u32x4;

__device__ __forceinline__ uint16_t f2bf(float f) {
  uint32_t u = __builtin_bit_cast(uint32_t, f);
  u += 0x7fffu + ((u >> 16) & 1u);
  return (uint16_t)(u >> 16);
}
__device__ __forceinline__ float bf2f(uint16_t h) {
  return __builtin_bit_cast(float, (uint32_t)h << 16);
}
__device__ __forceinline__ uint32_t cvtpk(float lo, float hi) {
  uint32_t r;
  asm("v_cvt_pk_bf16_f32 %0, %1, %2" : "=v"(r) : "v"(lo), "v"(hi));
  return r;
}

// XOR swizzles (involutions) for 128B/256B LDS rows
__device__ __forceinline__ uint32_t swz128(uint32_t a) { return a ^ (((a >> 7) & 7u) << 4); }
__device__ __forceinline__ uint32_t swz256(uint32_t a) { return a ^ (((a >> 8) & 7u) << 4); }

#define GAS __attribute__((address_space(1)))
#define LAS __attribute__((address_space(3)))
__device__ __forceinline__ void gload_lds16(const void* g, void* l) {
  __builtin_amdgcn_global_load_lds((GAS const void*)g, (LAS void*)l, 16, 0, 0);
}

// ---------------- fp32 -> bf16 convert (hs + 4 weight matrices, one launch) ----------------
__global__ void cvt_all_kernel(const float* __restrict__ hs,
                               const float* __restrict__ W0, const float* __restrict__ W1,
                               const float* __restrict__ W2, const float* __restrict__ W3,
                               uint16_t* __restrict__ Xbf, uint16_t* __restrict__ Wb) {
  const int bid = blockIdx.x;
  const float* src; uint16_t* dst;
  if (bid < 4096) {
    src = hs + (size_t)bid * 2048;
    dst = Xbf + (size_t)bid * 2048;
  } else {
    const int m = (bid - 4096) >> 11;
    const int blk = (bid - 4096) & 2047;
    const float* Ws = (m == 0) ? W0 : (m == 1) ? W1 : (m == 2) ? W2 : W3;
    src = Ws + (size_t)blk * 2048;
    dst = Wb + (size_t)m * HDIM * HDIM + (size_t)blk * 2048;
  }
  const float4* p = (const float4*)src + (size_t)threadIdx.x * 2;
  float4 a = p[0], b = p[1];
  uint32_t w0 = f2bf(a.x) | ((uint32_t)f2bf(a.y) << 16);
  uint32_t w1 = f2bf(a.z) | ((uint32_t)f2bf(a.w) << 16);
  uint32_t w2 = f2bf(b.x) | ((uint32_t)f2bf(b.y) << 16);
  uint32_t w3 = f2bf(b.z) | ((uint32_t)f2bf(b.w) << 16);
  int4 r; r.x = (int)w0; r.y = (int)w1; r.z = (int)w2; r.w = (int)w3;
  *(int4*)(dst + (size_t)threadIdx.x * 8) = r;
}

// ---------------- RoPE in-place on k only (q rope fused into attn) ----------------
__global__ void rope_kernel(uint16_t* __restrict__ kb,
                            const float* __restrict__ fcos, const float* __restrict__ fsin) {
  uint32_t i = blockIdx.x * 256 + threadIdx.x;
  uint16_t* p = kb + (size_t)i * 8;
  uint32_t e0 = i * 8;
  uint32_t row = e0 >> 11;
  uint32_t col = e0 & 2047;
  uint32_t s = row & (SEQ - 1);
  uint32_t pi = (col & (DHEAD - 1)) >> 1;
  float4 cv = *(const float4*)(fcos + (size_t)s * 64 + pi);
  float4 sv = *(const float4*)(fsin + (size_t)s * 64 + pi);
  int4 raw = *(const int4*)p;
  uint16_t u[8]; *(int4*)u = raw;
  float cc[4] = {cv.x, cv.y, cv.z, cv.w}, ss[4] = {sv.x, sv.y, sv.z, sv.w};
#pragma unroll
  for (int t = 0; t < 4; ++t) {
    float x0 = bf2f(u[2 * t]), x1 = bf2f(u[2 * t + 1]);
    float o0 = x0 * cc[t] - x1 * ss[t];
    float o1 = x0 * ss[t] + x1 * cc[t];
    u[2 * t] = f2bf(o0); u[2 * t + 1] = f2bf(o1);
  }
  *(int4*)p = *(int4*)u;
}

// ---------------- GEMM (BK=64, 16x16x32 MFMA, measured 1005 TF / 0 conflicts) ----------------
template <int MODE>
__device__ __forceinline__ void gemm_body(const uint16_t* __restrict__ A,
                                          const uint16_t* __restrict__ Bw,
                                          const float* __restrict__ bias,
                                          void* __restrict__ Cout) {
  __shared__ __align__(16) char smA[128 * 128];
  __shared__ __align__(16) char smB[128 * 128];
  const int tid = threadIdx.x, lane = tid & 63, wid = tid >> 6;
  const int c = lane & 15, g = lane >> 4;
  const int row0 = blockIdx.x * 128, col0 = blockIdx.y * 128;
  const int wr = wid >> 1, wc = wid & 1;
  f32x4 acc[4][4] = {};
  const uint32_t oBase = wid * 4096 + lane * 16;

  for (int kk = 0; kk < GK; kk += 64) {
#pragma unroll
    for (int q = 0; q < 4; ++q) {
      uint32_t o = oBase + q * 1024;
      uint32_t r = o >> 7;
      uint32_t cb = (o & 127) ^ ((r & 7u) << 4);
      gload_lds16((const char*)A + ((size_t)(row0 + r) * GK + kk) * 2 + cb,
                  smA + wid * 4096 + q * 1024);
      gload_lds16((const char*)Bw + ((size_t)(col0 + r) * GK + kk) * 2 + cb,
                  smB + wid * 4096 + q * 1024);
    }
    __syncthreads();
    short8 af[4][2], bf[4][2];
#pragma unroll
    for (int m = 0; m < 4; ++m) {
      const uint32_t row = (uint32_t)(wr * 64 + m * 16 + c);
#pragma unroll
      for (int ks = 0; ks < 2; ++ks)
        af[m][ks] = *(const short8*)(smA + row * 128 + (((uint32_t)(ks * 64 + g * 16)) ^ ((row & 7u) << 4)));
    }
#pragma unroll
    for (int n = 0; n < 4; ++n) {
      const uint32_t row = (uint32_t)(wc * 64 + n * 16 + c);
#pragma unroll
      for (int ks = 0; ks < 2; ++ks)
        bf[n][ks] = *(const short8*)(smB + row * 128 + (((uint32_t)(ks * 64 + g * 16)) ^ ((row & 7u) << 4)));
    }
#pragma unroll
    for (int m = 0; m < 4; ++m)
#pragma unroll
      for (int n = 0; n < 4; ++n)
#pragma unroll
        for (int ks = 0; ks < 2; ++ks)
          acc[m][n] = __builtin_amdgcn_mfma_f32_16x16x32_bf16(af[m][ks], bf[n][ks], acc[m][n], 0, 0, 0);
    __syncthreads();
  }

  float bn[4];
#pragma unroll
  for (int n = 0; n < 4; ++n) bn[n] = bias[col0 + wc * 64 + n * 16 + c];
#pragma unroll
  for (int m = 0; m < 4; ++m) {
    const int gr = row0 + wr * 64 + m * 16 + g * 4;
#pragma unroll
    for (int n = 0; n < 4; ++n) {
      const int gc = col0 + wc * 64 + n * 16 + c;
#pragma unroll
      for (int jj = 0; jj < 4; ++jj) {
        float v = acc[m][n][jj] + bn[n];
        if (MODE == 1) ((float*)Cout)[(size_t)(gr + jj) * GN + gc] = v;
        else           ((uint16_t*)Cout)[(size_t)(gr + jj) * GN + gc] = f2bf(v);
      }
    }
  }
}

__global__ __launch_bounds__(256, 2) void gemm_qkv_kernel(
    const uint16_t* __restrict__ X,
    const uint16_t* __restrict__ Wq, const uint16_t* __restrict__ Wk, const uint16_t* __restrict__ Wv,
    const float* __restrict__ bq, const float* __restrict__ bk, const float* __restrict__ bv,
    uint16_t* __restrict__ qo, uint16_t* __restrict__ ko, uint16_t* __restrict__ vo) {
  const uint16_t* W; const float* bias; uint16_t* out;
  if (blockIdx.z == 0)      { W = Wq; bias = bq; out = qo; }
  else if (blockIdx.z == 1) { W = Wk; bias = bk; out = ko; }
  else                      { W = Wv; bias = bv; out = vo; }
  gemm_body<0>(X, W, bias, out);
}

__global__ __launch_bounds__(256, 2) void gemm_out_kernel(
    const uint16_t* __restrict__ ctx, const uint16_t* __restrict__ Wo,
    const float* __restrict__ bo, float* __restrict__ out) {
  gemm_body<1>(ctx, Wo, bo, out);
}

// ---------------- flash attention v7 (session best): 512 thr, 8 waves, dbuf pipeline ----------------
__global__ __launch_bounds__(512, 2) void attn_kernel(
    const uint16_t* __restrict__ q, const uint16_t* __restrict__ k,
    const uint16_t* __restrict__ v, const float* __restrict__ mask,
    const float* __restrict__ fcos, const float* __restrict__ fsin,
    uint16_t* __restrict__ ctx) {
  __shared__ __align__(16) char pool[66048];
  float* smT = (float*)pool;  // epilogue only

  const int tid = threadIdx.x, lane = tid & 63, wid = tid >> 6;  // wid 0..7
  const int c32 = lane & 31, hi = lane >> 5;
  const int lb = (blockIdx.x & 7) * 32 + (blockIdx.x >> 3);
  const int qt = lb & 3, bh = lb >> 2;
  const int h = bh & (NHEAD - 1), b = bh >> 4;
  const int q0 = qt * 256;
  const float scale = 0.022097086912079608f;  // 1/sqrt(2048)

  short8 qreg[8];
  {
    const int srow = q0 + wid * 32 + c32;
    const uint16_t* qrow = q + (size_t)(b * SEQ + srow) * HDIM + h * DHEAD;
#pragma unroll
    for (int ks = 0; ks < 8; ++ks) {
      short8 raw = *(const short8*)(qrow + ks * 16 + hi * 8);
      float4 cv = *(const float4*)(fcos + (size_t)srow * 64 + ks * 8 + hi * 4);
      float4 sv = *(const float4*)(fsin + (size_t)srow * 64 + ks * 8 + hi * 4);
      uint16_t u[8]; *(short8*)u = raw;
      float cc[4] = {cv.x, cv.y, cv.z, cv.w}, ssv[4] = {sv.x, sv.y, sv.z, sv.w};
#pragma unroll
      for (int tp = 0; tp < 4; ++tp) {
        float x0 = bf2f(u[2 * tp]), x1 = bf2f(u[2 * tp + 1]);
        u[2 * tp]     = f2bf(x0 * cc[tp] - x1 * ssv[tp]);
        u[2 * tp + 1] = f2bf(x0 * ssv[tp] + x1 * cc[tp]);
      }
      qreg[ks] = *(short8*)u;
    }
  }

  const int kvq = tid >> 5;          // V-transpose: 4 kv x 4 d per thread
  const int d0v = (tid & 31) * 4;

  auto issueK = [&](int s) {   // 8 waves x 2 gloads = 64 rows
    char* dK = pool + (s & 1) * 16384;
#pragma unroll
    for (int i = 0; i < 2; ++i) {
      uint32_t o_ = wid * 2048 + i * 1024 + lane * 16;
      uint32_t r = o_ >> 8;
      uint32_t cb = swz256(o_) & 255;
      gload_lds16((const char*)k + ((size_t)(b * SEQ + s * 64 + r) * HDIM + h * DHEAD) * 2 + cb,
                  dK + wid * 2048 + i * 1024);
    }
  };
  auto loadV = [&](int s, uint32_t vw[4][2]) {
    const uint16_t* vsrc = v + (size_t)(b * SEQ + s * 64 + kvq * 4) * HDIM + h * DHEAD + d0v;
#pragma unroll
    for (int e = 0; e < 4; ++e) {
      uint2 t2 = *(const uint2*)(vsrc + (size_t)e * HDIM);
      vw[e][0] = t2.x; vw[e][1] = t2.y;
    }
  };
  auto writeVT = [&](int s, uint32_t vw[4][2]) {
    char* dVT = pool + 32768 + (s & 1) * 16384;
#pragma unroll
    for (int j = 0; j < 4; ++j) {
      const int hw = j >> 1, sh = (j & 1) * 16;
      uint2 pk;
      pk.x = ((vw[0][hw] >> sh) & 0xffffu) | (((vw[1][hw] >> sh) & 0xffffu) << 16);
      pk.y = ((vw[2][hw] >> sh) & 0xffffu) | (((vw[3][hw] >> sh) & 0xffffu) << 16);
      *(uint2*)(dVT + swz128((uint32_t)((d0v + j) * 128 + kvq * 8))) = pk;
    }
  };

  float mreg = -1e30f, lreg = 0.f;
  f32x16 o[4] = {};

  {
    float mtmp = 0.f;
    if (tid < 64) mtmp = mask[b * SEQ + tid];
    uint32_t vw[4][2];
    loadV(0, vw);
    issueK(0);
    if (tid < 64) ((float*)(pool + 65536))[tid] = mtmp;
    writeVT(0, vw);
  }
  __syncthreads();

  for (int t = 0; t < 16; ++t) {
    const int cur = t & 1;
    const char* sK  = pool + cur * 16384;
    const char* sVT = pool + 32768 + cur * 16384;
    const float* smMaskF = (const float*)(pool + 65536 + cur * 256);

    float mtmp = 0.f;
    uint32_t vw[4][2];
    if (t < 15) {
      if (tid < 64) mtmp = mask[b * SEQ + (t + 1) * 64 + tid];
      loadV(t + 1, vw);
      issueK(t + 1);
    }

    f32x16 st[2] = {};
    __builtin_amdgcn_s_setprio(1);
#pragma unroll
    for (int ks = 0; ks < 8; ++ks) {
#pragma unroll
      for (int mi = 0; mi < 2; ++mi) {
        const uint32_t row = (uint32_t)(mi * 32 + c32);
        short8 kf = *(const short8*)(sK + row * 256 +
                    (((uint32_t)(ks * 32 + hi * 16)) ^ ((row & 7u) << 4)));
        st[mi] = __builtin_amdgcn_mfma_f32_32x32x16_bf16(kf, qreg[ks], st[mi], 0, 0, 0);
      }
    }
    __builtin_amdgcn_s_setprio(0);

    float pmax = -1e30f;
#pragma unroll
    for (int mi = 0; mi < 2; ++mi) {
      const float* mb = smMaskF + mi * 32 + hi * 4;
      float4 m0 = *(const float4*)(mb);
      float4 m1 = *(const float4*)(mb + 8);
      float4 m2 = *(const float4*)(mb + 16);
      float4 m3 = *(const float4*)(mb + 24);
      float mm[16] = {m0.x, m0.y, m0.z, m0.w, m1.x, m1.y, m1.z, m1.w,
                      m2.x, m2.y, m2.z, m2.w, m3.x, m3.y, m3.z, m3.w};
#pragma unroll
      for (int r = 0; r < 16; ++r) {
        float s = st[mi][r] * scale;
        if (mm[r] == 0.f) s = -1e9f;
        st[mi][r] = s;
        pmax = fmaxf(pmax, s);
      }
    }
    pmax = fmaxf(pmax, __shfl_xor(pmax, 32, 64));

    if (!__all(pmax <= mreg + 8.f)) {
      float mnew = fmaxf(mreg, pmax);
      float fac = __expf(mreg - mnew);
      lreg *= fac;
#pragma unroll
      for (int dt = 0; dt < 4; ++dt)
#pragma unroll
        for (int e = 0; e < 16; ++e) o[dt][e] *= fac;
      mreg = mnew;
    }

    float rsum = 0.f;
    short8 pfrag[4];
#pragma unroll
    for (int mi = 0; mi < 2; ++mi) {
      float pe[16];
#pragma unroll
      for (int r = 0; r < 16; ++r) {
        pe[r] = __expf(st[mi][r] - mreg);
        rsum += pe[r];
      }
      uint32_t w[8], s[8];
#pragma unroll
      for (int j = 0; j < 8; ++j) w[j] = cvtpk(pe[2 * j], pe[2 * j + 1]);
#pragma unroll
      for (int j = 0; j < 8; ++j) s[j] = (uint32_t)__shfl_xor((int)w[j], 32, 64);
      u32x4 f0, f1;
      f0[0] = hi ? s[2] : w[0];  f0[1] = hi ? s[3] : w[1];
      f0[2] = hi ? w[2] : s[0];  f0[3] = hi ? w[3] : s[1];
      f1[0] = hi ? s[6] : w[4];  f1[1] = hi ? s[7] : w[5];
      f1[2] = hi ? w[6] : s[4];  f1[3] = hi ? w[7] : s[5];
      pfrag[mi * 2]     = __builtin_bit_cast(short8, f0);
      pfrag[mi * 2 + 1] = __builtin_bit_cast(short8, f1);
    }
    rsum += __shfl_xor(rsum, 32, 64);
    lreg += rsum;

    if (t < 15) {
      if (tid < 64) ((float*)(pool + 65536 + ((t + 1) & 1) * 256))[tid] = mtmp;
      writeVT(t + 1, vw);
    }

    __builtin_amdgcn_s_setprio(1);
#pragma unroll
    for (int dt = 0; dt < 4; ++dt) {
      const uint32_t row = (uint32_t)(dt * 32 + c32);
#pragma unroll
      for (int e = 0; e < 4; ++e) {
        short8 vf = *(const short8*)(sVT + row * 128 +
                    (((uint32_t)(e * 32 + hi * 16)) ^ ((row & 7u) << 4)));
        o[dt] = __builtin_amdgcn_mfma_f32_32x32x16_bf16(vf, pfrag[e], o[dt], 0, 0, 0);
      }
    }
    __builtin_amdgcn_s_setprio(0);

    __syncthreads();
  }

  const float linv = 1.f / lreg;
  float* myT = smT + wid * (32 * 36);
  const int qe = lane >> 1, de0 = (lane & 1) * 16;
#pragma unroll
  for (int dt = 0; dt < 4; ++dt) {
#pragma unroll
    for (int r = 0; r < 16; ++r) {
      const int drow = (r & 3) + 8 * (r >> 2) + 4 * hi;
      myT[c32 * 36 + drow] = o[dt][r] * linv;   // [q][d]
    }
    float vv[16];
#pragma unroll
    for (int j = 0; j < 4; ++j) {
      float4 rd = *(const float4*)(myT + qe * 36 + de0 + j * 4);
      vv[j * 4 + 0] = rd.x; vv[j * 4 + 1] = rd.y; vv[j * 4 + 2] = rd.z; vv[j * 4 + 3] = rd.w;
    }
    uint32_t pw[8];
#pragma unroll
    for (int m = 0; m < 8; ++m)
      pw[m] = f2bf(vv[2 * m]) | ((uint32_t)f2bf(vv[2 * m + 1]) << 16);
    uint16_t* dst = ctx + (size_t)(b * SEQ + q0 + wid * 32 + qe) * HDIM + h * DHEAD + dt * 32 + de0;
    int4 s0; s0.x = (int)pw[0]; s0.y = (int)pw[1]; s0.z = (int)pw[2]; s0.w = (int)pw[3];
    int4 s1; s1.x = (int)pw[4]; s1.y = (int)pw[5]; s1.z = (int)pw[6]; s1.w = (int)pw[7];
    *(int4*)(dst) = s0;
    *(int4*)(dst + 8) = s1;
  }
}

// ---------------- launch ----------------
extern "C" void kernel_launch(void* const* d_in, const int* in_sizes, int n_in,
                              void* d_out, int out_size, void* d_ws, size_t ws_size,
                              hipStream_t stream) {
  const float* hs   = (const float*)d_in[0];
  const float* fcos = (const float*)d_in[1];
  const float* fsin = (const float*)d_in[2];
  const float* mask = (const float*)d_in[3];
  const float* Wq = (const float*)d_in[4];  const float* bq = (const float*)d_in[5];
  const float* Wk = (const float*)d_in[6];  const float* bk = (const float*)d_in[7];
  const float* Wv = (const float*)d_in[8];  const float* bv = (const float*)d_in[9];
  const float* Wo = (const float*)d_in[10]; const float* bo = (const float*)d_in[11];
  float* out = (float*)d_out;

  char* ws = (char*)d_ws;
  const size_t XB = (size_t)GM * HDIM * 2;    // 16 MB
  const size_t WB = (size_t)HDIM * HDIM * 2;  //  8 MB
  uint16_t* Xbf = (uint16_t*)(ws);            // reused as ctx after QKV
  uint16_t* Wqb = (uint16_t*)(ws + XB);       // Wqb..Wob contiguous
  uint16_t* Wkb = (uint16_t*)(ws + XB + WB);
  uint16_t* Wvb = (uint16_t*)(ws + XB + 2 * WB);
  uint16_t* Wob = (uint16_t*)(ws + XB + 3 * WB);
  uint16_t* qb  = (uint16_t*)(ws + XB + 4 * WB);
  uint16_t* kb  = (uint16_t*)(ws + XB + 4 * WB + XB);
  uint16_t* vb  = (uint16_t*)(ws + XB + 4 * WB + 2 * XB);

  cvt_all_kernel<<<12288, 256, 0, stream>>>(hs, Wq, Wk, Wv, Wo, Xbf, Wqb);

  gemm_qkv_kernel<<<dim3(GM / 128, GN / 128, 3), 256, 0, stream>>>(
      Xbf, Wqb, Wkb, Wvb, bq, bk, bv, qb, kb, vb);

  rope_kernel<<<dim3((GM * HDIM) / 8 / 256, 1, 1), 256, 0, stream>>>(kb, fcos, fsin);

  attn_kernel<<<256, 512, 0, stream>>>(qb, kb, vb, mask, fcos, fsin, Xbf);

  gemm_out_kernel<<<dim3(GM / 128, GN / 128, 1), 256, 0, stream>>>(Xbf, Wob, bo, out);
}